// Round 13
// baseline (154.192 us; speedup 1.0000x reference)
//
#include <hip/hip_runtime.h>
#include <hip/hip_bf16.h>

// TDCPQueryAttentionPool fused kernel for MI355X (gfx950).
// B=8, N=4096, M=4, E=512, H=8, d=64. tokens = 32768.
//
// R13: x staged as RAW F32 via global_load_lds DMA (no VGPR cost -> deep
// in-flight queue), 3 rotating 32KB LDS buffers (dynamic 112KB), DMA 2
// steps ahead, B-frags reg-loaded 1 step ahead (R7 pattern). bf16 cvt
// fused into A-frag reads (2x ds_read_b128 + cvt_pk, bit-identical RNE).
// Swizzle: linear LDS dest + inverse-swizzled per-lane GLOBAL src
// (unit ^= row&7), same XOR on read. Waits: steady wbv12/WAITV(12),
// tails 8/8/0. Epilogue verbatim R7 (av/stats moved to buf2 region).

typedef float  f32x4  __attribute__((ext_vector_type(4)));
typedef float  f32x16 __attribute__((ext_vector_type(16)));
typedef short  short8 __attribute__((ext_vector_type(8)));

typedef __attribute__((address_space(1))) const void GV;
typedef __attribute__((address_space(3))) void LV;

__device__ __forceinline__ unsigned short f2bf(float f) {
  unsigned int x = __float_as_uint(f);
  unsigned int r = (x + 0x7fffu + ((x >> 16) & 1u)) >> 16;  // RNE
  return (unsigned short)r;
}

__device__ __forceinline__ short8 pack8(const f32x4& a, const f32x4& b) {
  unsigned int r0, r1, r2, r3;
  asm("v_cvt_pk_bf16_f32 %0, %1, %2" : "=v"(r0) : "v"(a[0]), "v"(a[1]));
  asm("v_cvt_pk_bf16_f32 %0, %1, %2" : "=v"(r1) : "v"(a[2]), "v"(a[3]));
  asm("v_cvt_pk_bf16_f32 %0, %1, %2" : "=v"(r2) : "v"(b[0]), "v"(b[1]));
  asm("v_cvt_pk_bf16_f32 %0, %1, %2" : "=v"(r3) : "v"(b[2]), "v"(b[3]));
  short8 r;
  r[0] = (short)(r0 & 0xffff); r[1] = (short)(r0 >> 16);
  r[2] = (short)(r1 & 0xffff); r[3] = (short)(r1 >> 16);
  r[4] = (short)(r2 & 0xffff); r[5] = (short)(r2 >> 16);
  r[6] = (short)(r3 & 0xffff); r[7] = (short)(r3 >> 16);
  return r;
}

__device__ __forceinline__ void mfma32(f32x16& c, short8 a, short8 b) {
  asm("v_mfma_f32_32x32x16_bf16 %0, %1, %2, %0" : "+v"(c) : "v"(a), "v"(b));
}
__device__ __forceinline__ void mfma16(f32x4& c, short8 a, short8 b) {
  asm("v_mfma_f32_16x16x32_bf16 %0, %1, %2, %0" : "+v"(c) : "v"(a), "v"(b));
}

__device__ __forceinline__ void gld4s(short8& d, const unsigned short* p) {
  asm volatile("global_load_dwordx4 %0, %1, off" : "=v"(d) : "v"(p));
}

#define WAITV(n) asm volatile("s_waitcnt vmcnt(" #n ")" ::: "memory")

__device__ __forceinline__ void wbv12(short8& a, short8& b, short8& c, short8& d,
                                      short8& e, short8& f, short8& g, short8& h) {
  asm volatile("s_waitcnt vmcnt(12)"
               : "+v"(a), "+v"(b), "+v"(c), "+v"(d),
                 "+v"(e), "+v"(f), "+v"(g), "+v"(h));
}
__device__ __forceinline__ void wbv8(short8& a, short8& b, short8& c, short8& d,
                                     short8& e, short8& f, short8& g, short8& h) {
  asm volatile("s_waitcnt vmcnt(8)"
               : "+v"(a), "+v"(b), "+v"(c), "+v"(d),
                 "+v"(e), "+v"(f), "+v"(g), "+v"(h));
}
__device__ __forceinline__ void wbv0(short8& a, short8& b, short8& c, short8& d,
                                     short8& e, short8& f, short8& g, short8& h) {
  asm volatile("s_waitcnt vmcnt(0)"
               : "+v"(a), "+v"(b), "+v"(c), "+v"(d),
                 "+v"(e), "+v"(f), "+v"(g), "+v"(h));
}

// ---------------------------------------------------------------------------
// K0: precompute (verbatim from R1-R12; correctness-verified).
// ---------------------------------------------------------------------------
__global__ void __launch_bounds__(512) tdcp_k0(
    const float* __restrict__ q_param, const float* __restrict__ in_w,
    const float* __restrict__ in_b, const float* __restrict__ out_w,
    float* __restrict__ scoreb, unsigned short* __restrict__ wscB,
    unsigned short* __restrict__ WvB, unsigned short* __restrict__ WoB)
{
  const int tid = threadIdx.x;
  const int blk = blockIdx.x;
  if (blk < 8) {
    const int h = blk;
    __shared__ float qls[512];
    __shared__ float qs[64];
    qls[tid] = q_param[tid];
    __syncthreads();
    {
      const int io = tid >> 3, sub = tid & 7;
      const float* wrow = in_w + (size_t)(h * 64 + io) * 512;
      float v = 0.f;
      #pragma unroll 8
      for (int ee = 0; ee < 64; ++ee) {
        const int e = sub + (ee << 3);
        v += wrow[e] * qls[e];
      }
      v += __shfl_xor(v, 1); v += __shfl_xor(v, 2); v += __shfl_xor(v, 4);
      if (sub == 0) qs[io] = (v + in_b[h * 64 + io]) * 0.125f;
    }
    __syncthreads();
    {
      const int e = tid;
      const float* wk = in_w + (size_t)(512 + h * 64) * 512 + e;
      float v = 0.f;
      #pragma unroll 8
      for (int jj = 0; jj < 64; ++jj) v += qs[jj] * wk[jj * 512];
      const int s32 = e >> 5, g = (e & 31) >> 3, j = e & 7;
      wscB[((s32 << 6) + h + (g << 4)) * 8 + j] = f2bf(v);
      wscB[((s32 << 6) + (h + 8) + (g << 4)) * 8 + j] = 0;
    }
    if (tid < 64) {
      float v = qs[tid] * in_b[512 + h * 64 + tid];
      v += __shfl_xor(v, 1);  v += __shfl_xor(v, 2);  v += __shfl_xor(v, 4);
      v += __shfl_xor(v, 8);  v += __shfl_xor(v, 16); v += __shfl_xor(v, 32);
      if (tid == 0) scoreb[h] = v;
    }
    if (blk == 0 && tid >= 64 && tid < 72) scoreb[tid - 56] = 0.f;
  } else {
    const int mb = blk - 8;
    const bool isWo = mb >= 64;
    const float* src = isWo ? out_w : (in_w + (size_t)1024 * 512);
    unsigned short* dst = isWo ? WoB : WvB;
    const int slot = ((mb & 63) << 9) + tid;
    const int ct = slot >> 11, kt = (slot >> 6) & 31, ln = slot & 63;
    const float* p = src + (size_t)(ct * 32 + (ln & 31)) * 512
                         + kt * 16 + ((ln >> 5) << 3);
    const f32x4 u0 = *(const f32x4*)(p);
    const f32x4 u1 = *(const f32x4*)(p + 4);
    short8 rr;
    rr[0] = (short)f2bf(u0[0]); rr[1] = (short)f2bf(u0[1]);
    rr[2] = (short)f2bf(u0[2]); rr[3] = (short)f2bf(u0[3]);
    rr[4] = (short)f2bf(u1[0]); rr[5] = (short)f2bf(u1[1]);
    rr[6] = (short)f2bf(u1[2]); rr[7] = (short)f2bf(u1[3]);
    *(short8*)(dst + slot * 8) = rr;
  }
}

// ---------------------------------------------------------------------------
// K1: fused attention-pool, f32-DMA staging + counted vmcnt.
// Dynamic LDS 112KB: bufs @0/@32K/@64K (32KB each, f32, row-major 128x64
// with 32B-unit swizzle u^=row&7); wsc @98304.
// Epilogue: omid @0 (buf0), av @65536 (buf2), stats @69632.
// DMA map: wave w stages rows [16w,16w+16); instr q covers rows 16w+4q..+3;
// lane l -> row R=16w+4q+(l>>4), phys 16B slot (l&15); global src unit
// u = ((l&15)>>1) ^ (R&7), half = l&1.
// ---------------------------------------------------------------------------
__global__ void __launch_bounds__(512, 2) tdcp_k1(
    const float* __restrict__ f0, const float* __restrict__ f1,
    const float* __restrict__ f2, const float* __restrict__ f3,
    const float* __restrict__ in_b,
    const float* __restrict__ scoreb, const unsigned short* __restrict__ wscB,
    const unsigned short* __restrict__ WvB, const unsigned short* __restrict__ WoB,
    const float* __restrict__ out_b, const float* __restrict__ gamma,
    const float* __restrict__ beta, float* __restrict__ out)
{
  extern __shared__ __align__(16) char smem[];
  const int tid = threadIdx.x;
  const int w = tid >> 6;         // wave 0..7: owns output cols [64w,64w+64)
  const int l = tid & 63;
  const int tok0 = blockIdx.x << 5;

  // ---- wsc -> LDS @98304 (16 KB) ----
  {
    const f32x4* wsrc = (const f32x4*)wscB;
    f32x4* wdst = (f32x4*)(smem + 98304);
    wdst[tid * 2] = wsrc[tid * 2];
    wdst[tid * 2 + 1] = wsrc[tid * 2 + 1];
  }

  // ---- DMA source pointers (4 instr/wave/step, 16B/lane) ----
  const float* gsrc[4];
  #pragma unroll
  for (int q = 0; q < 4; ++q) {
    const int R = 16 * w + 4 * q + (l >> 4);
    const int m = R & 3, tok = R >> 2;
    const int u = (((l & 15) >> 1) ^ (R & 7));
    gsrc[q] = (m == 0 ? f0 : m == 1 ? f1 : m == 2 ? f2 : f3)
              + (size_t)(tok0 + tok) * 512 + (u << 3) + ((l & 1) << 2);
  }
  const int dmaDst = (w << 12);   // wave's 4KB within buffer

  // ---- fragment-read offsets (f32 LDS, swizzled) ----
  const int aB = (l & 31) << 8;                       // row-in-tile * 256B
  int offA[4];
  #pragma unroll
  for (int kt4 = 0; kt4 < 4; ++kt4)
    offA[kt4] = (((2 * kt4 + (l >> 5)) ^ (l & 7)) << 5);
  const int sB = (16 * w + (l & 15)) << 8;
  int offS[2];
  #pragma unroll
  for (int sc = 0; sc < 2; ++sc)
    offS[sc] = (((4 * sc + (l >> 4)) ^ (l & 7)) << 5);

  const int ct0 = w << 1;
  const unsigned short* wv0 = WvB + (((ct0 * 32) << 6) + l) * 8;
  const unsigned short* wv1 = WvB + ((((ct0 + 1) * 32) << 6) + l) * 8;
  const unsigned short* wscL = (const unsigned short*)(smem + 98304);

  f32x16 acc[4][2];
  f32x4 sacc;
  #pragma unroll
  for (int i = 0; i < 4; ++i)
    #pragma unroll
    for (int cc = 0; cc < 2; ++cc)
      #pragma unroll
      for (int r = 0; r < 16; ++r) acc[i][cc][r] = 0.f;
  sacc[0] = sacc[1] = sacc[2] = sacc[3] = 0.f;

  short8 bb[2][8];

#define DMA(S) do { \
    char* db_ = smem + 32768 * ((S) % 3) + dmaDst; \
    __builtin_amdgcn_global_load_lds((GV*)(gsrc[0] + (S) * 64), (LV*)(db_),        16, 0, 0); \
    __builtin_amdgcn_global_load_lds((GV*)(gsrc[1] + (S) * 64), (LV*)(db_ + 1024), 16, 0, 0); \
    __builtin_amdgcn_global_load_lds((GV*)(gsrc[2] + (S) * 64), (LV*)(db_ + 2048), 16, 0, 0); \
    __builtin_amdgcn_global_load_lds((GV*)(gsrc[3] + (S) * 64), (LV*)(db_ + 3072), 16, 0, 0); \
  } while (0)

#define ISSUE_B(S, bank) do { \
    gld4s(bb[bank][0], wv0 + ((S) * 4 + 0) * 512); \
    gld4s(bb[bank][1], wv1 + ((S) * 4 + 0) * 512); \
    gld4s(bb[bank][2], wv0 + ((S) * 4 + 1) * 512); \
    gld4s(bb[bank][3], wv1 + ((S) * 4 + 1) * 512); \
    gld4s(bb[bank][4], wv0 + ((S) * 4 + 2) * 512); \
    gld4s(bb[bank][5], wv1 + ((S) * 4 + 2) * 512); \
    gld4s(bb[bank][6], wv0 + ((S) * 4 + 3) * 512); \
    gld4s(bb[bank][7], wv1 + ((S) * 4 + 3) * 512); \
  } while (0)

  // ---- prologue: D0,D1, B0; drain D0 (12 newer); lgkm; barrier ----
  DMA(0); DMA(1);
  ISSUE_B(0, 0);
  WAITV(12);
  asm volatile("s_waitcnt lgkmcnt(0)" ::: "memory");
  __builtin_amdgcn_s_barrier();
  asm volatile("" ::: "memory");

  // ---- main loop: 8 steps of 64 e-elements ----
  #pragma unroll
  for (int s = 0; s < 8; ++s) {
    if (s < 6) DMA(s + 2);
    if (s < 7) ISSUE_B(s + 1, (s + 1) & 1);

    short8 (&b)[8] = bb[s & 1];
    if (s < 6)      wbv12(b[0], b[1], b[2], b[3], b[4], b[5], b[6], b[7]);
    else if (s == 6) wbv8(b[0], b[1], b[2], b[3], b[4], b[5], b[6], b[7]);
    else             wbv0(b[0], b[1], b[2], b[3], b[4], b[5], b[6], b[7]);

    const char* cur = smem + 32768 * (s % 3);
    const short8 sb0 = *(const short8*)(wscL + (((2 * s) << 6) + l) * 8);
    const short8 sb1 = *(const short8*)(wscL + (((2 * s + 1) << 6) + l) * 8);
    #pragma unroll
    for (int kt4 = 0; kt4 < 4; ++kt4) {
      #pragma unroll
      for (int rt = 0; rt < 4; ++rt) {
        const char* p = cur + (rt << 13) + aB + offA[kt4];
        const f32x4 lo = *(const f32x4*)(p);
        const f32x4 hi = *(const f32x4*)(p + 16);
        const short8 a = pack8(lo, hi);
        mfma32(acc[rt][0], a, b[kt4 * 2]);
        mfma32(acc[rt][1], a, b[kt4 * 2 + 1]);
      }
      if ((kt4 & 1) == 0) {
        const int sc = kt4 >> 1;
        const char* p = cur + sB + offS[sc];
        const f32x4 lo = *(const f32x4*)(p);
        const f32x4 hi = *(const f32x4*)(p + 16);
        mfma16(sacc, pack8(lo, hi), (sc == 0) ? sb0 : sb1);
      }
    }

    if (s < 6)      { WAITV(12); }   // drain D(s+1): newer = D(s+2)4 + B(s+1)8
    else if (s == 6) { WAITV(8); }   // drain D(7):   newer = B(7)8
    if (s < 7) {
      asm volatile("s_waitcnt lgkmcnt(0)" ::: "memory");
      __builtin_amdgcn_s_barrier();
      asm volatile("" ::: "memory");
    }
  }
  asm volatile("s_nop 7\n\ts_nop 7\n\ts_nop 7" ::);  // MFMA->VALU hazard pad

  // ---- softmax over m (lane-local), write av[t][h] to LDS @65536 ----
  {
    const int hh = l & 15;
    if (hh < 8) {
      const float sb = scoreb[hh];
      const float s0 = sacc[0] + sb, s1 = sacc[1] + sb;
      const float s2 = sacc[2] + sb, s3 = sacc[3] + sb;
      const float mx = fmaxf(fmaxf(s0, s1), fmaxf(s2, s3));
      const float e0 = __expf(s0 - mx), e1 = __expf(s1 - mx);
      const float e2 = __expf(s2 - mx), e3 = __expf(s3 - mx);
      const float inv = 1.f / (e0 + e1 + e2 + e3);
      f32x4 av; av[0] = e0 * inv; av[1] = e1 * inv; av[2] = e2 * inv; av[3] = e3 * inv;
      const int t = (w << 2) + (l >> 4);
      *(f32x4*)(smem + 65536 + (((t << 3) + hh) << 4)) = av;
    }
  }
  __syncthreads();

  // ---- blend: o_mid[t][f] = sum_m av*V + bv; scatter to frag LDS @0 ----
  {
    unsigned short* omid = (unsigned short*)(smem);
    #pragma unroll
    for (int c2 = 0; c2 < 2; ++c2) {
      const int ff = ((ct0 + c2) << 5) + (l & 31);
      const float bvf = in_b[1024 + ff];
      const int ktf = ff >> 4;
      const int laneL = ((l >> 3) & 1) << 5;
      const int elem = ff & 7;
      #pragma unroll
      for (int rt = 0; rt < 4; ++rt) {
        #pragma unroll
        for (int tt = 0; tt < 4; ++tt) {
          const int t = (rt << 3) + (tt << 1) + (l >> 5);
          const f32x4 av = *(const f32x4*)(smem + 65536 + (((t << 3) + w) << 4));
          const float o = av[0] * acc[rt][c2][tt * 4 + 0]
                        + av[1] * acc[rt][c2][tt * 4 + 1]
                        + av[2] * acc[rt][c2][tt * 4 + 2]
                        + av[3] * acc[rt][c2][tt * 4 + 3] + bvf;
          omid[((ktf << 6) + t + laneL) * 8 + elem] = f2bf(o);
        }
      }
    }
  }
  __syncthreads();

  // ---- out-projection GEMM: [32 x 512] x Wo^T (unroll 4, verified) ----
  f32x16 oa0, oa1;
  #pragma unroll
  for (int r = 0; r < 16; ++r) { oa0[r] = 0.f; oa1[r] = 0.f; }
  const unsigned short* wo0 = WoB + (((ct0 * 32) << 6) + l) * 8;
  const unsigned short* wo1 = WoB + ((((ct0 + 1) * 32) << 6) + l) * 8;
  const int a_off = l << 4;
  #pragma unroll 4
  for (int kt = 0; kt < 32; ++kt) {
    const short8 a = *(const short8*)(smem + (kt << 10) + a_off);
    mfma32(oa0, a, *(const short8*)(wo0 + kt * 512));
    mfma32(oa1, a, *(const short8*)(wo1 + kt * 512));
  }
  asm volatile("s_nop 7\n\ts_nop 7\n\ts_nop 7" ::);  // MFMA->VALU hazard pad

  // ---- LayerNorm: per-wave partial stats -> LDS @69632 -> combine -> store ----
  {
    const int g0 = (ct0 << 5) + (l & 31);
    const int g1 = g0 + 32;
    const float ob0 = out_b[g0], ob1 = out_b[g1];
    const float gm0 = gamma[g0], gm1 = gamma[g1];
    const float bt0 = beta[g0],  bt1 = beta[g1];
    float* stats = (float*)(smem + 69632);  // [32][8 waves][2]
    #pragma unroll
    for (int r = 0; r < 16; ++r) {
      const float v0 = oa0[r] + ob0, v1 = oa1[r] + ob1;
      float s = v0 + v1, qq = v0 * v0 + v1 * v1;
      s += __shfl_xor(s, 16); qq += __shfl_xor(qq, 16);
      s += __shfl_xor(s, 8);  qq += __shfl_xor(qq, 8);
      s += __shfl_xor(s, 4);  qq += __shfl_xor(qq, 4);
      s += __shfl_xor(s, 2);  qq += __shfl_xor(qq, 2);
      s += __shfl_xor(s, 1);  qq += __shfl_xor(qq, 1);
      if ((l & 31) == 0) {
        const int t = (r & 3) + ((r >> 2) << 3) + ((l >> 5) << 2);
        stats[(t << 4) + (w << 1)] = s;
        stats[(t << 4) + (w << 1) + 1] = qq;
      }
    }
    __syncthreads();
    #pragma unroll
    for (int r = 0; r < 16; ++r) {
      const int t = (r & 3) + ((r >> 2) << 3) + ((l >> 5) << 2);
      const float* st = stats + (t << 4);
      float s = 0.f, qq = 0.f;
      #pragma unroll
      for (int ww = 0; ww < 8; ++ww) { s += st[2 * ww]; qq += st[2 * ww + 1]; }
      const float mu = s * 0.001953125f;
      const float rs = rsqrtf(qq * 0.001953125f - mu * mu + 1e-5f);
      const float v0 = oa0[r] + ob0, v1 = oa1[r] + ob1;
      float* op = out + (size_t)(tok0 + t) * 512;
      op[g0] = (v0 - mu) * rs * gm0 + bt0;
      op[g1] = (v1 - mu) * rs * gm1 + bt1;
    }
  }
#undef DMA
#undef ISSUE_B
}

extern "C" void kernel_launch(void* const* d_in, const int* in_sizes, int n_in,
                              void* d_out, int out_size, void* d_ws, size_t ws_size,
                              hipStream_t stream) {
  const float* f0      = (const float*)d_in[0];
  const float* f1      = (const float*)d_in[1];
  const float* f2      = (const float*)d_in[2];
  const float* f3      = (const float*)d_in[3];
  const float* q_param = (const float*)d_in[4];
  const float* in_w    = (const float*)d_in[5];
  const float* in_b    = (const float*)d_in[6];
  const float* out_w   = (const float*)d_in[7];
  const float* out_b   = (const float*)d_in[8];
  const float* gamma   = (const float*)d_in[9];
  const float* beta    = (const float*)d_in[10];
  float* out = (float*)d_out;

  char* ws = (char*)d_ws;
  float* scoreb          = (float*)ws;                      // 64 B
  unsigned short* wscB   = (unsigned short*)(ws + 4096);    // 16 KB
  unsigned short* WvB    = (unsigned short*)(ws + 20480);   // 512 KB
  unsigned short* WoB    = (unsigned short*)(ws + 544768);  // 512 KB

  // Unconditional, deterministic, host-side (R9-proven pattern).
  hipFuncSetAttribute((const void*)tdcp_k1,
                      hipFuncAttributeMaxDynamicSharedMemorySize, 114688);

  tdcp_k0<<<136, 512, 0, stream>>>(q_param, in_w, in_b, out_w,
                                   scoreb, wscB, WvB, WoB);
  tdcp_k1<<<1024, 512, 114688, stream>>>(f0, f1, f2, f3, in_b,
                                         scoreb, wscB, WvB, WoB,
                                         out_b, gamma, beta, out);
}

// Round 14
// 151.215 us; speedup vs baseline: 1.0197x; 1.0197x over previous
//
#include <hip/hip_runtime.h>
#include <hip/hip_bf16.h>

// TDCPQueryAttentionPool fused kernel for MI355X (gfx950).
// B=8, N=4096, M=4, E=512, H=8, d=64. tokens = 32768.
//
// R14: barrier-count test. R13's DMA staging (f32 x via global_load_lds,
// zero staging registers) with 2 steps merged into 1: 4 steps x 128 e,
// 5 barriers/block (was 9). Two 64KB x-buffers + wsc = 144KB dynamic LDS.
// Queue invariant 24->16 at every wait: steady {wbv16,wbv16,WAITV(16)},
// tail {wbv8,wbv0}, prologue WAITV(16). All addressing verbatim R13
// (each 64KB buf = two R13 32KB sub-buffers).

typedef float  f32x4  __attribute__((ext_vector_type(4)));
typedef float  f32x16 __attribute__((ext_vector_type(16)));
typedef short  short8 __attribute__((ext_vector_type(8)));

typedef __attribute__((address_space(1))) const void GV;
typedef __attribute__((address_space(3))) void LV;

__device__ __forceinline__ unsigned short f2bf(float f) {
  unsigned int x = __float_as_uint(f);
  unsigned int r = (x + 0x7fffu + ((x >> 16) & 1u)) >> 16;  // RNE
  return (unsigned short)r;
}

__device__ __forceinline__ short8 pack8(const f32x4& a, const f32x4& b) {
  unsigned int r0, r1, r2, r3;
  asm("v_cvt_pk_bf16_f32 %0, %1, %2" : "=v"(r0) : "v"(a[0]), "v"(a[1]));
  asm("v_cvt_pk_bf16_f32 %0, %1, %2" : "=v"(r1) : "v"(a[2]), "v"(a[3]));
  asm("v_cvt_pk_bf16_f32 %0, %1, %2" : "=v"(r2) : "v"(b[0]), "v"(b[1]));
  asm("v_cvt_pk_bf16_f32 %0, %1, %2" : "=v"(r3) : "v"(b[2]), "v"(b[3]));
  short8 r;
  r[0] = (short)(r0 & 0xffff); r[1] = (short)(r0 >> 16);
  r[2] = (short)(r1 & 0xffff); r[3] = (short)(r1 >> 16);
  r[4] = (short)(r2 & 0xffff); r[5] = (short)(r2 >> 16);
  r[6] = (short)(r3 & 0xffff); r[7] = (short)(r3 >> 16);
  return r;
}

__device__ __forceinline__ void mfma32(f32x16& c, short8 a, short8 b) {
  asm("v_mfma_f32_32x32x16_bf16 %0, %1, %2, %0" : "+v"(c) : "v"(a), "v"(b));
}
__device__ __forceinline__ void mfma16(f32x4& c, short8 a, short8 b) {
  asm("v_mfma_f32_16x16x32_bf16 %0, %1, %2, %0" : "+v"(c) : "v"(a), "v"(b));
}

__device__ __forceinline__ void gld4s(short8& d, const unsigned short* p) {
  asm volatile("global_load_dwordx4 %0, %1, off" : "=v"(d) : "v"(p));
}

#define WAITV(n) asm volatile("s_waitcnt vmcnt(" #n ")" ::: "memory")

__device__ __forceinline__ void wbv16(short8& a, short8& b, short8& c, short8& d,
                                      short8& e, short8& f, short8& g, short8& h) {
  asm volatile("s_waitcnt vmcnt(16)"
               : "+v"(a), "+v"(b), "+v"(c), "+v"(d),
                 "+v"(e), "+v"(f), "+v"(g), "+v"(h));
}
__device__ __forceinline__ void wbv8(short8& a, short8& b, short8& c, short8& d,
                                     short8& e, short8& f, short8& g, short8& h) {
  asm volatile("s_waitcnt vmcnt(8)"
               : "+v"(a), "+v"(b), "+v"(c), "+v"(d),
                 "+v"(e), "+v"(f), "+v"(g), "+v"(h));
}
__device__ __forceinline__ void wbv0(short8& a, short8& b, short8& c, short8& d,
                                     short8& e, short8& f, short8& g, short8& h) {
  asm volatile("s_waitcnt vmcnt(0)"
               : "+v"(a), "+v"(b), "+v"(c), "+v"(d),
                 "+v"(e), "+v"(f), "+v"(g), "+v"(h));
}

// ---------------------------------------------------------------------------
// K0: precompute (verbatim from R1-R13; correctness-verified).
// ---------------------------------------------------------------------------
__global__ void __launch_bounds__(512) tdcp_k0(
    const float* __restrict__ q_param, const float* __restrict__ in_w,
    const float* __restrict__ in_b, const float* __restrict__ out_w,
    float* __restrict__ scoreb, unsigned short* __restrict__ wscB,
    unsigned short* __restrict__ WvB, unsigned short* __restrict__ WoB)
{
  const int tid = threadIdx.x;
  const int blk = blockIdx.x;
  if (blk < 8) {
    const int h = blk;
    __shared__ float qls[512];
    __shared__ float qs[64];
    qls[tid] = q_param[tid];
    __syncthreads();
    {
      const int io = tid >> 3, sub = tid & 7;
      const float* wrow = in_w + (size_t)(h * 64 + io) * 512;
      float v = 0.f;
      #pragma unroll 8
      for (int ee = 0; ee < 64; ++ee) {
        const int e = sub + (ee << 3);
        v += wrow[e] * qls[e];
      }
      v += __shfl_xor(v, 1); v += __shfl_xor(v, 2); v += __shfl_xor(v, 4);
      if (sub == 0) qs[io] = (v + in_b[h * 64 + io]) * 0.125f;
    }
    __syncthreads();
    {
      const int e = tid;
      const float* wk = in_w + (size_t)(512 + h * 64) * 512 + e;
      float v = 0.f;
      #pragma unroll 8
      for (int jj = 0; jj < 64; ++jj) v += qs[jj] * wk[jj * 512];
      const int s32 = e >> 5, g = (e & 31) >> 3, j = e & 7;
      wscB[((s32 << 6) + h + (g << 4)) * 8 + j] = f2bf(v);
      wscB[((s32 << 6) + (h + 8) + (g << 4)) * 8 + j] = 0;
    }
    if (tid < 64) {
      float v = qs[tid] * in_b[512 + h * 64 + tid];
      v += __shfl_xor(v, 1);  v += __shfl_xor(v, 2);  v += __shfl_xor(v, 4);
      v += __shfl_xor(v, 8);  v += __shfl_xor(v, 16); v += __shfl_xor(v, 32);
      if (tid == 0) scoreb[h] = v;
    }
    if (blk == 0 && tid >= 64 && tid < 72) scoreb[tid - 56] = 0.f;
  } else {
    const int mb = blk - 8;
    const bool isWo = mb >= 64;
    const float* src = isWo ? out_w : (in_w + (size_t)1024 * 512);
    unsigned short* dst = isWo ? WoB : WvB;
    const int slot = ((mb & 63) << 9) + tid;
    const int ct = slot >> 11, kt = (slot >> 6) & 31, ln = slot & 63;
    const float* p = src + (size_t)(ct * 32 + (ln & 31)) * 512
                         + kt * 16 + ((ln >> 5) << 3);
    const f32x4 u0 = *(const f32x4*)(p);
    const f32x4 u1 = *(const f32x4*)(p + 4);
    short8 rr;
    rr[0] = (short)f2bf(u0[0]); rr[1] = (short)f2bf(u0[1]);
    rr[2] = (short)f2bf(u0[2]); rr[3] = (short)f2bf(u0[3]);
    rr[4] = (short)f2bf(u1[0]); rr[5] = (short)f2bf(u1[1]);
    rr[6] = (short)f2bf(u1[2]); rr[7] = (short)f2bf(u1[3]);
    *(short8*)(dst + slot * 8) = rr;
  }
}

// ---------------------------------------------------------------------------
// K1: fused attention-pool, f32-DMA staging, 4 steps x 128e, 5 barriers.
// Dynamic LDS 144KB: buf0 @0, buf1 @64K (each = two 32KB R13 sub-bufs,
// row-major 128x64 f32, 32B-unit swizzle u^=row&7); wsc @128K.
// Epilogue: omid @0, av @32K, stats @36K (buf0 region; last step reads buf1).
// ---------------------------------------------------------------------------
__global__ void __launch_bounds__(512, 2) tdcp_k1(
    const float* __restrict__ f0, const float* __restrict__ f1,
    const float* __restrict__ f2, const float* __restrict__ f3,
    const float* __restrict__ in_b,
    const float* __restrict__ scoreb, const unsigned short* __restrict__ wscB,
    const unsigned short* __restrict__ WvB, const unsigned short* __restrict__ WoB,
    const float* __restrict__ out_b, const float* __restrict__ gamma,
    const float* __restrict__ beta, float* __restrict__ out)
{
  extern __shared__ __align__(16) char smem[];
  const int tid = threadIdx.x;
  const int w = tid >> 6;         // wave 0..7: owns output cols [64w,64w+64)
  const int l = tid & 63;
  const int tok0 = blockIdx.x << 5;

  // ---- wsc -> LDS @131072 (16 KB) ----
  {
    const f32x4* wsrc = (const f32x4*)wscB;
    f32x4* wdst = (f32x4*)(smem + 131072);
    wdst[tid * 2] = wsrc[tid * 2];
    wdst[tid * 2 + 1] = wsrc[tid * 2 + 1];
  }

  // ---- DMA source pointers (verbatim R13) ----
  const float* gsrc[4];
  #pragma unroll
  for (int q = 0; q < 4; ++q) {
    const int R = 16 * w + 4 * q + (l >> 4);
    const int m = R & 3, tok = R >> 2;
    const int u = (((l & 15) >> 1) ^ (R & 7));
    gsrc[q] = (m == 0 ? f0 : m == 1 ? f1 : m == 2 ? f2 : f3)
              + (size_t)(tok0 + tok) * 512 + (u << 3) + ((l & 1) << 2);
  }
  const int dmaDst = (w << 12);   // wave's 4KB within each 32KB sub-buffer

  // ---- fragment-read offsets (verbatim R13) ----
  const int aB = (l & 31) << 8;
  int offA[4];
  #pragma unroll
  for (int kt4 = 0; kt4 < 4; ++kt4)
    offA[kt4] = (((2 * kt4 + (l >> 5)) ^ (l & 7)) << 5);
  const int sB = (16 * w + (l & 15)) << 8;
  int offS[2];
  #pragma unroll
  for (int sc = 0; sc < 2; ++sc)
    offS[sc] = (((4 * sc + (l >> 4)) ^ (l & 7)) << 5);

  const int ct0 = w << 1;
  const unsigned short* wv0 = WvB + (((ct0 * 32) << 6) + l) * 8;
  const unsigned short* wv1 = WvB + ((((ct0 + 1) * 32) << 6) + l) * 8;
  const unsigned short* wscL = (const unsigned short*)(smem + 131072);

  f32x16 acc[4][2];
  f32x4 sacc;
  #pragma unroll
  for (int i = 0; i < 4; ++i)
    #pragma unroll
    for (int cc = 0; cc < 2; ++cc)
      #pragma unroll
      for (int r = 0; r < 16; ++r) acc[i][cc][r] = 0.f;
  sacc[0] = sacc[1] = sacc[2] = sacc[3] = 0.f;

  short8 bb[2][8];   // bank = e-group half within the 128e step

// DMA one 128e step SP (0..3): 8 instrs, two 64e groups into the two
// 32KB sub-buffers of buf (SP&1).
#define DMA(SP) do { \
    char* db_ = smem + 65536 * ((SP) & 1) + dmaDst; \
    __builtin_amdgcn_global_load_lds((GV*)(gsrc[0] + (2*(SP)) * 64),     (LV*)(db_),                16, 0, 0); \
    __builtin_amdgcn_global_load_lds((GV*)(gsrc[1] + (2*(SP)) * 64),     (LV*)(db_ + 1024),         16, 0, 0); \
    __builtin_amdgcn_global_load_lds((GV*)(gsrc[2] + (2*(SP)) * 64),     (LV*)(db_ + 2048),         16, 0, 0); \
    __builtin_amdgcn_global_load_lds((GV*)(gsrc[3] + (2*(SP)) * 64),     (LV*)(db_ + 3072),         16, 0, 0); \
    __builtin_amdgcn_global_load_lds((GV*)(gsrc[0] + (2*(SP)+1) * 64),   (LV*)(db_ + 32768),        16, 0, 0); \
    __builtin_amdgcn_global_load_lds((GV*)(gsrc[1] + (2*(SP)+1) * 64),   (LV*)(db_ + 32768 + 1024), 16, 0, 0); \
    __builtin_amdgcn_global_load_lds((GV*)(gsrc[2] + (2*(SP)+1) * 64),   (LV*)(db_ + 32768 + 2048), 16, 0, 0); \
    __builtin_amdgcn_global_load_lds((GV*)(gsrc[3] + (2*(SP)+1) * 64),   (LV*)(db_ + 32768 + 3072), 16, 0, 0); \
  } while (0)

// B-frags for 64e group G (0..7) into bank k.
#define ISSUE_B(G, k) do { \
    gld4s(bb[k][0], wv0 + ((G) * 4 + 0) * 512); \
    gld4s(bb[k][1], wv1 + ((G) * 4 + 0) * 512); \
    gld4s(bb[k][2], wv0 + ((G) * 4 + 1) * 512); \
    gld4s(bb[k][3], wv1 + ((G) * 4 + 1) * 512); \
    gld4s(bb[k][4], wv0 + ((G) * 4 + 2) * 512); \
    gld4s(bb[k][5], wv1 + ((G) * 4 + 2) * 512); \
    gld4s(bb[k][6], wv0 + ((G) * 4 + 3) * 512); \
    gld4s(bb[k][7], wv1 + ((G) * 4 + 3) * 512); \
  } while (0)

// Compute one 64e group: sub-buffer curE, B bank k, wsc group G.
#define COMPUTE_EG(curE, k, G) do { \
    const short8 sb0_ = *(const short8*)(wscL + (((2*(G)) << 6) + l) * 8); \
    const short8 sb1_ = *(const short8*)(wscL + (((2*(G)+1) << 6) + l) * 8); \
    _Pragma("unroll") \
    for (int kt4 = 0; kt4 < 4; ++kt4) { \
      _Pragma("unroll") \
      for (int rt = 0; rt < 4; ++rt) { \
        const char* p_ = (curE) + (rt << 13) + aB + offA[kt4]; \
        const f32x4 lo_ = *(const f32x4*)(p_); \
        const f32x4 hi_ = *(const f32x4*)(p_ + 16); \
        const short8 a_ = pack8(lo_, hi_); \
        mfma32(acc[rt][0], a_, bb[k][kt4 * 2]); \
        mfma32(acc[rt][1], a_, bb[k][kt4 * 2 + 1]); \
      } \
      if ((kt4 & 1) == 0) { \
        const int sc_ = kt4 >> 1; \
        const char* p_ = (curE) + sB + offS[sc_]; \
        const f32x4 lo_ = *(const f32x4*)(p_); \
        const f32x4 hi_ = *(const f32x4*)(p_ + 16); \
        mfma16(sacc, pack8(lo_, hi_), (sc_ == 0) ? sb0_ : sb1_); \
      } \
    } \
  } while (0)

#define WB16(k) wbv16(bb[k][0], bb[k][1], bb[k][2], bb[k][3], \
                      bb[k][4], bb[k][5], bb[k][6], bb[k][7])
#define WB8(k)  wbv8(bb[k][0], bb[k][1], bb[k][2], bb[k][3], \
                     bb[k][4], bb[k][5], bb[k][6], bb[k][7])
#define WB0(k)  wbv0(bb[k][0], bb[k][1], bb[k][2], bb[k][3], \
                     bb[k][4], bb[k][5], bb[k][6], bb[k][7])

  // ---- prologue: DMA(0):8, B(0)->bank0:8, B(1)->bank1:8; drain DMA(0) ----
  DMA(0);
  ISSUE_B(0, 0);
  ISSUE_B(1, 1);
  WAITV(16);
  asm volatile("s_waitcnt lgkmcnt(0)" ::: "memory");
  __builtin_amdgcn_s_barrier();
  asm volatile("" ::: "memory");

  // ---- main loop: 4 steps of 128 e-elements ----
  #pragma unroll
  for (int s = 0; s < 4; ++s) {
    if (s < 3) DMA(s + 1);                          // [B0:8,B1:8,D:8]=24
    char* buf = smem + 65536 * (s & 1);

    // e-group 0
    if (s < 3) WB16(0);                             // drain B(s,0); newer=16
    else       WB8(0);                              // newer = B(3,1) only
    COMPUTE_EG(buf, 0, 4 * s + 0 - 2 * s);          // G = 2s
    if (s < 3) ISSUE_B(2 * (s + 1), 0);             // [B1,D,nB0]=24

    // e-group 1
    if (s < 3) WB16(1);                             // drain B(s,1); newer=16
    else       WB0(1);
    COMPUTE_EG(buf + 32768, 1, 2 * s + 1);          // G = 2s+1
    if (s < 3) ISSUE_B(2 * (s + 1) + 1, 1);         // [D,nB0,nB1]=24

    if (s < 3) {
      WAITV(16);                                    // drain DMA(s+1); newer=16
      asm volatile("s_waitcnt lgkmcnt(0)" ::: "memory");
      __builtin_amdgcn_s_barrier();
      asm volatile("" ::: "memory");
    }
  }
  asm volatile("s_nop 7\n\ts_nop 7\n\ts_nop 7" ::);  // MFMA->VALU hazard pad

  // ---- softmax over m (lane-local), write av[t][h] to LDS @32K ----
  {
    const int hh = l & 15;
    if (hh < 8) {
      const float sb = scoreb[hh];
      const float s0 = sacc[0] + sb, s1 = sacc[1] + sb;
      const float s2 = sacc[2] + sb, s3 = sacc[3] + sb;
      const float mx = fmaxf(fmaxf(s0, s1), fmaxf(s2, s3));
      const float e0 = __expf(s0 - mx), e1 = __expf(s1 - mx);
      const float e2 = __expf(s2 - mx), e3 = __expf(s3 - mx);
      const float inv = 1.f / (e0 + e1 + e2 + e3);
      f32x4 av; av[0] = e0 * inv; av[1] = e1 * inv; av[2] = e2 * inv; av[3] = e3 * inv;
      const int t = (w << 2) + (l >> 4);
      *(f32x4*)(smem + 32768 + (((t << 3) + hh) << 4)) = av;
    }
  }
  __syncthreads();

  // ---- blend: o_mid[t][f] = sum_m av*V + bv; scatter to frag LDS @0 ----
  {
    unsigned short* omid = (unsigned short*)(smem);
    #pragma unroll
    for (int c2 = 0; c2 < 2; ++c2) {
      const int ff = ((ct0 + c2) << 5) + (l & 31);
      const float bvf = in_b[1024 + ff];
      const int ktf = ff >> 4;
      const int laneL = ((l >> 3) & 1) << 5;
      const int elem = ff & 7;
      #pragma unroll
      for (int rt = 0; rt < 4; ++rt) {
        #pragma unroll
        for (int tt = 0; tt < 4; ++tt) {
          const int t = (rt << 3) + (tt << 1) + (l >> 5);
          const f32x4 av = *(const f32x4*)(smem + 32768 + (((t << 3) + w) << 4));
          const float o = av[0] * acc[rt][c2][tt * 4 + 0]
                        + av[1] * acc[rt][c2][tt * 4 + 1]
                        + av[2] * acc[rt][c2][tt * 4 + 2]
                        + av[3] * acc[rt][c2][tt * 4 + 3] + bvf;
          omid[((ktf << 6) + t + laneL) * 8 + elem] = f2bf(o);
        }
      }
    }
  }
  __syncthreads();

  // ---- out-projection GEMM: [32 x 512] x Wo^T (unroll 4, verified) ----
  f32x16 oa0, oa1;
  #pragma unroll
  for (int r = 0; r < 16; ++r) { oa0[r] = 0.f; oa1[r] = 0.f; }
  const unsigned short* wo0 = WoB + (((ct0 * 32) << 6) + l) * 8;
  const unsigned short* wo1 = WoB + ((((ct0 + 1) * 32) << 6) + l) * 8;
  const int a_off = l << 4;
  #pragma unroll 4
  for (int kt = 0; kt < 32; ++kt) {
    const short8 a = *(const short8*)(smem + (kt << 10) + a_off);
    mfma32(oa0, a, *(const short8*)(wo0 + kt * 512));
    mfma32(oa1, a, *(const short8*)(wo1 + kt * 512));
  }
  asm volatile("s_nop 7\n\ts_nop 7\n\ts_nop 7" ::);  // MFMA->VALU hazard pad

  // ---- LayerNorm: per-wave partial stats -> LDS @36K -> combine -> store ----
  {
    const int g0 = (ct0 << 5) + (l & 31);
    const int g1 = g0 + 32;
    const float ob0 = out_b[g0], ob1 = out_b[g1];
    const float gm0 = gamma[g0], gm1 = gamma[g1];
    const float bt0 = beta[g0],  bt1 = beta[g1];
    float* stats = (float*)(smem + 36864);  // [32][8 waves][2]
    #pragma unroll
    for (int r = 0; r < 16; ++r) {
      const float v0 = oa0[r] + ob0, v1 = oa1[r] + ob1;
      float s = v0 + v1, qq = v0 * v0 + v1 * v1;
      s += __shfl_xor(s, 16); qq += __shfl_xor(qq, 16);
      s += __shfl_xor(s, 8);  qq += __shfl_xor(qq, 8);
      s += __shfl_xor(s, 4);  qq += __shfl_xor(qq, 4);
      s += __shfl_xor(s, 2);  qq += __shfl_xor(qq, 2);
      s += __shfl_xor(s, 1);  qq += __shfl_xor(qq, 1);
      if ((l & 31) == 0) {
        const int t = (r & 3) + ((r >> 2) << 3) + ((l >> 5) << 2);
        stats[(t << 4) + (w << 1)] = s;
        stats[(t << 4) + (w << 1) + 1] = qq;
      }
    }
    __syncthreads();
    #pragma unroll
    for (int r = 0; r < 16; ++r) {
      const int t = (r & 3) + ((r >> 2) << 3) + ((l >> 5) << 2);
      const float* st = stats + (t << 4);
      float s = 0.f, qq = 0.f;
      #pragma unroll
      for (int ww = 0; ww < 8; ++ww) { s += st[2 * ww]; qq += st[2 * ww + 1]; }
      const float mu = s * 0.001953125f;
      const float rs = rsqrtf(qq * 0.001953125f - mu * mu + 1e-5f);
      const float v0 = oa0[r] + ob0, v1 = oa1[r] + ob1;
      float* op = out + (size_t)(tok0 + t) * 512;
      op[g0] = (v0 - mu) * rs * gm0 + bt0;
      op[g1] = (v1 - mu) * rs * gm1 + bt1;
    }
  }
#undef DMA
#undef ISSUE_B
#undef COMPUTE_EG
#undef WB16
#undef WB8
#undef WB0
}

extern "C" void kernel_launch(void* const* d_in, const int* in_sizes, int n_in,
                              void* d_out, int out_size, void* d_ws, size_t ws_size,
                              hipStream_t stream) {
  const float* f0      = (const float*)d_in[0];
  const float* f1      = (const float*)d_in[1];
  const float* f2      = (const float*)d_in[2];
  const float* f3      = (const float*)d_in[3];
  const float* q_param = (const float*)d_in[4];
  const float* in_w    = (const float*)d_in[5];
  const float* in_b    = (const float*)d_in[6];
  const float* out_w   = (const float*)d_in[7];
  const float* out_b   = (const float*)d_in[8];
  const float* gamma   = (const float*)d_in[9];
  const float* beta    = (const float*)d_in[10];
  float* out = (float*)d_out;

  char* ws = (char*)d_ws;
  float* scoreb          = (float*)ws;                      // 64 B
  unsigned short* wscB   = (unsigned short*)(ws + 4096);    // 16 KB
  unsigned short* WvB    = (unsigned short*)(ws + 20480);   // 512 KB
  unsigned short* WoB    = (unsigned short*)(ws + 544768);  // 512 KB

  // Unconditional, deterministic, host-side (R9/R13-proven pattern).
  hipFuncSetAttribute((const void*)tdcp_k1,
                      hipFuncAttributeMaxDynamicSharedMemorySize, 147456);

  tdcp_k0<<<136, 512, 0, stream>>>(q_param, in_w, in_b, out_w,
                                   scoreb, wscB, WvB, WoB);
  tdcp_k1<<<1024, 512, 147456, stream>>>(f0, f1, f2, f3, in_b,
                                         scoreb, wscB, WvB, WoB,
                                         out_b, gamma, beta, out);
}